// Round 8
// baseline (549.117 us; speedup 1.0000x reference)
//
#include <hip/hip_runtime.h>
#include <math.h>

#define HASH_SIZE_LOG2 19
#define HASH_MASK ((1u << HASH_SIZE_LOG2) - 1u)
#define HS (1u << HASH_SIZE_LOG2)
#define NUM_LEVELS 16
#define NFULL 11                // levels 5..15: full-footprint tables in gather
#define NSMALL 5                // levels 0..4: gathered in transpose (L2-resident)
#define CHUNK 2048              // points per gather block
#define PPT 8                   // points per thread in gather

typedef float f32x2 __attribute__((ext_vector_type(2)));
typedef float f32x4 __attribute__((ext_vector_type(4)));

struct ResArr { float r[NUM_LEVELS]; };

// Static schedule for full levels 5..15: 11 levels x 8 eighths = 88 tasks ->
// 8 XCDs x 11 slots, exactly uniform. Same-level tasks adjacent in slot
// order so each XCD streams through <=2-3 distinct 4MB tables sequentially
// (one at a time L2-resident).
struct Sched {
    unsigned char lvl[88];    // [xcd][slot] slot=0..10
    unsigned char oct[88];    // eighth index 0..7
    ResArr res;
};

// ---------------- Phase 1: balanced level-pinned gather into ws[l-5][n] ----
// bid = (slot*ochunks + c)*8 + xcd ; XCD(bid) = bid%8 (round-robin dispatch).
// Table loads are NON-TEMPORAL: L1 hit rate is ~0 for a 4MB table, so skip
// the 64B L1 line fill per 8B gather (tests the L1-fill-serialization
// hypothesis); the table stays L2-resident via XCD pinning.
__global__ __launch_bounds__(256) void he_gather_kernel(
    const float* __restrict__ x,      // [N,3]
    const float* __restrict__ emb,    // [16][HS][2]
    f32x2* __restrict__ ws,           // [11][N]
    Sched sc, int n_points, int ochunks, int chunks)
{
    __shared__ float sx[CHUNK * 3];

    const int bid = blockIdx.x;
    const int xcd = bid & 7;
    const int r = bid >> 3;
    const int slot = r / ochunks;
    const int c = r - slot * ochunks;
    const int lvl = sc.lvl[xcd * NFULL + slot];
    const int chunk = (int)sc.oct[xcd * NFULL + slot] * ochunks + c;
    if (chunk >= chunks) return;

    const long long base = (long long)chunk * CHUNK;
    const int t = threadIdx.x;

    // cooperative nt load of this chunk's x (1536 f32x4 = 24KB)
    const f32x4* x4 = (const f32x4*)x;
    const long long nflt4 = ((long long)n_points * 3) / 4;
    for (int i = t; i < CHUNK * 3 / 4; i += 256) {
        long long gi = (long long)chunk * (CHUNK * 3 / 4) + i;
        f32x4 v = (gi < nflt4) ? __builtin_nontemporal_load(&x4[gi])
                               : (f32x4){0, 0, 0, 0};
        ((f32x4*)sx)[i] = v;
    }
    __syncthreads();

    const float rl = sc.res.r[lvl];                      // wave-uniform
    const f32x2* __restrict__ table = (const f32x2*)emb + (size_t)lvl * HS;
    f32x2* __restrict__ wsl = ws + (size_t)(lvl - NSMALL) * n_points;
    const unsigned P1 = 2654435761u, P2 = 805459861u;

    unsigned h[PPT];
    #pragma unroll
    for (int j = 0; j < PPT; j++) {
        const int p = t + j * 256;
        // exact f32 multiply+floor (matches jnp.floor(x*res) in f32);
        // int64 hash % 2^19 == uint32-wrapped sum & mask (2^19 | 2^32).
        unsigned c0 = (unsigned)(int)floorf(sx[p * 3 + 0] * rl);
        unsigned c1 = (unsigned)(int)floorf(sx[p * 3 + 1] * rl);
        unsigned c2 = (unsigned)(int)floorf(sx[p * 3 + 2] * rl);
        h[j] = (c0 + c1 * P1 + c2 * P2) & HASH_MASK;
    }
    f32x2 f[PPT];
    #pragma unroll
    for (int j = 0; j < PPT; j++)
        f[j] = __builtin_nontemporal_load(&table[h[j]]);  // L2-resident, skip L1
    #pragma unroll
    for (int j = 0; j < PPT; j++) {
        const long long n = base + t + j * 256;
        if (n < n_points) __builtin_nontemporal_store(f[j], &wsl[n]);
    }
}

// ------ Phase 2: transpose ws[11][N] -> out[N][32] + gather small levels ---
// Small tables (levels 0..4, 1.8MB total) are L2-resident on every XCD;
// their gathers mostly hit L2 and overlap the streaming.
__global__ __launch_bounds__(256) void he_transpose_kernel(
    const f32x2* __restrict__ ws,     // [11][N]
    const float* __restrict__ x,      // [N,3]
    const float* __restrict__ emb,    // [16][HS][2]
    float* __restrict__ out,          // [N,32]
    ResArr res, int n_points)
{
    __shared__ f32x2 sf[256 * 17];    // stride 17 f32x2: conflict-free
    __shared__ float sxx[256 * 3];
    const long long base = (long long)blockIdx.x * 256;
    const int t = threadIdx.x;
    const long long n = base + t;

    // coalesced x load for this tile (768 floats)
    for (int i = t; i < 768; i += 256) {
        long long gi = base * 3 + i;
        sxx[i] = (gi < (long long)n_points * 3) ? x[gi] : 0.0f;
    }
    __syncthreads();

    // small-level gathers (temporal: tables are small & reused)
    const float x0 = sxx[t * 3 + 0];
    const float x1 = sxx[t * 3 + 1];
    const float x2 = sxx[t * 3 + 2];
    const unsigned P1 = 2654435761u, P2 = 805459861u;
    const f32x2* __restrict__ e2 = (const f32x2*)emb;
    #pragma unroll
    for (int l = 0; l < NSMALL; l++) {
        const float rl = res.r[l];
        unsigned c0 = (unsigned)(int)floorf(x0 * rl);
        unsigned c1 = (unsigned)(int)floorf(x1 * rl);
        unsigned c2 = (unsigned)(int)floorf(x2 * rl);
        unsigned h = (c0 + c1 * P1 + c2 * P2) & HASH_MASK;
        sf[t * 17 + l] = e2[(size_t)l * HS + h];
    }
    // full levels from ws
    #pragma unroll
    for (int l = 0; l < NFULL; l++) {
        f32x2 v = (n < n_points)
            ? __builtin_nontemporal_load(&ws[(size_t)l * n_points + n])
            : (f32x2){0, 0};
        sf[t * 17 + NSMALL + l] = v;
    }
    __syncthreads();

    #pragma unroll
    for (int j = 0; j < 8; j++) {
        const int i = t + j * 256;     // f32x4 index within tile (0..2047)
        const int p = i >> 3;          // local point
        const int c2 = (i & 7) * 2;    // f32x2 offset in point row
        if (base + p < n_points) {
            f32x2 a = sf[p * 17 + c2];
            f32x2 b = sf[p * 17 + c2 + 1];
            f32x4 v = {a.x, a.y, b.x, b.y};
            __builtin_nontemporal_store(v, (f32x4*)out + (base * 8 + i));
        }
    }
}

// ---------------- Fallback (direct) if ws too small ------------------------
__global__ __launch_bounds__(256) void he_direct_kernel(
    const float* __restrict__ x, const float* __restrict__ emb,
    float* __restrict__ out, ResArr res, int n_points)
{
    __shared__ float sx[128 * 3];
    __shared__ float sres[NUM_LEVELS];
    const int t = threadIdx.x;
    const long long base = (long long)blockIdx.x * 128;
    if (t < NUM_LEVELS) sres[t] = res.r[t];
    for (int i = t; i < 384; i += 256) {
        long long gi = base * 3 + i;
        sx[i] = (gi < (long long)n_points * 3)
                    ? __builtin_nontemporal_load(&x[gi]) : 0.0f;
    }
    __syncthreads();
    const int lp = t & 7, pl = t >> 3, l0 = lp * 2;
    const float rA = sres[l0], rB = sres[l0 + 1];
    const unsigned P1 = 2654435761u, P2 = 805459861u;
    const f32x2* __restrict__ e2 = (const f32x2*)emb;
    unsigned ha[4], hb[4];
    #pragma unroll
    for (int j = 0; j < 4; j++) {
        const int pj = pl + j * 32;
        const float x0 = sx[pj * 3], x1 = sx[pj * 3 + 1], x2 = sx[pj * 3 + 2];
        unsigned a0 = (unsigned)(int)floorf(x0 * rA);
        unsigned a1 = (unsigned)(int)floorf(x1 * rA);
        unsigned a2 = (unsigned)(int)floorf(x2 * rA);
        unsigned b0 = (unsigned)(int)floorf(x0 * rB);
        unsigned b1 = (unsigned)(int)floorf(x1 * rB);
        unsigned b2 = (unsigned)(int)floorf(x2 * rB);
        ha[j] = (a0 + a1 * P1 + a2 * P2) & HASH_MASK;
        hb[j] = (b0 + b1 * P1 + b2 * P2) & HASH_MASK;
    }
    f32x2 fa[4], fb[4];
    #pragma unroll
    for (int j = 0; j < 4; j++) {
        fa[j] = e2[(size_t)l0 * HS + ha[j]];
        fb[j] = e2[((size_t)l0 + 1) * HS + hb[j]];
    }
    #pragma unroll
    for (int j = 0; j < 4; j++) {
        const long long n = base + pl + j * 32;
        if (n < n_points) {
            f32x4 v = {fa[j].x, fa[j].y, fb[j].x, fb[j].y};
            __builtin_nontemporal_store(v, (f32x4*)out + (n * 8 + lp));
        }
    }
}

extern "C" void kernel_launch(void* const* d_in, const int* in_sizes, int n_in,
                              void* d_out, int out_size, void* d_ws, size_t ws_size,
                              hipStream_t stream) {
    const float* x   = (const float*)d_in[0];
    const float* emb = (const float*)d_in[1];
    float* out = (float*)d_out;
    const int n = in_sizes[0] / 3;

    // Host-side RESOLUTIONS, identical arithmetic to the reference's Python
    // (libm pow + truncation) so level 15 (exact 2048.0) truncates identically.
    ResArr res;
    const double b = pow(128.0, 1.0 / 15.0);
    for (int i = 0; i < NUM_LEVELS; i++) {
        res.r[i] = (float)(long long)(16.0 * pow(b, (double)i));
    }

    const size_t ws_need = (size_t)NFULL * (size_t)n * sizeof(f32x2);
    if (ws_size >= ws_need) {
        Sched sc;
        sc.res = res;
        // full levels 5..15: 88 eighth-tasks -> exactly 11 per XCD,
        // same-level tasks adjacent in slot order.
        for (int q = 0; q < 88; q++) {
            int xcd = q / 11, slot = q % 11;
            sc.lvl[xcd * NFULL + slot] = (unsigned char)(5 + q / 8);
            sc.oct[xcd * NFULL + slot] = (unsigned char)(q % 8);
        }
        const int chunks = (n + CHUNK - 1) / CHUNK;
        const int ochunks = (chunks + 7) / 8;
        he_gather_kernel<<<8 * NFULL * ochunks, 256, 0, stream>>>(
            x, emb, (f32x2*)d_ws, sc, n, ochunks, chunks);
        he_transpose_kernel<<<(n + 255) / 256, 256, 0, stream>>>(
            (const f32x2*)d_ws, x, emb, out, res, n);
    } else {
        he_direct_kernel<<<(n + 127) / 128, 256, 0, stream>>>(x, emb, out, res, n);
    }
}

// Round 9
// 306.326 us; speedup vs baseline: 1.7926x; 1.7926x over previous
//
#include <hip/hip_runtime.h>
#include <math.h>

#define HASH_SIZE_LOG2 19
#define HASH_MASK ((1u << HASH_SIZE_LOG2) - 1u)
#define HS (1u << HASH_SIZE_LOG2)
#define NUM_LEVELS 16
#define NFULL 11                // levels 5..15: full-footprint tables in gather
#define NSMALL 5                // levels 0..4: gathered in transpose (L2-resident)
#define CHUNK 2048              // points per gather block
#define PPT 8                   // points per thread in gather

typedef float f32x2 __attribute__((ext_vector_type(2)));
typedef float f32x4 __attribute__((ext_vector_type(4)));

struct ResArr { float r[NUM_LEVELS]; };

// Static schedule for full levels 5..15: 11 levels x 8 eighths = 88 tasks ->
// 8 XCDs x 11 slots, exactly uniform. Same-level tasks adjacent in slot
// order so each XCD streams through <=2-3 distinct 4MB tables sequentially
// (one at a time L2-resident).
struct Sched {
    unsigned char lvl[88];    // [xcd][slot] slot=0..10
    unsigned char oct[88];    // eighth index 0..7
    ResArr res;
};

// ---------------- Phase 1: balanced level-pinned gather into ws[l-5][n] ----
// bid = (slot*ochunks + c)*8 + xcd ; XCD(bid) = bid%8 (round-robin dispatch).
// Table loads are TEMPORAL (round 8 lesson: the nt hint is evict-first in L2
// too, and destroys the pinned table's L2 residency -> FETCH 325MB->1GB).
// nt only on the streams we own: x reads, ws writes.
__global__ __launch_bounds__(256) void he_gather_kernel(
    const float* __restrict__ x,      // [N,3]
    const float* __restrict__ emb,    // [16][HS][2]
    f32x2* __restrict__ ws,           // [11][N]
    Sched sc, int n_points, int ochunks, int chunks)
{
    __shared__ float sx[CHUNK * 3];

    const int bid = blockIdx.x;
    const int xcd = bid & 7;
    const int r = bid >> 3;
    const int slot = r / ochunks;
    const int c = r - slot * ochunks;
    const int lvl = sc.lvl[xcd * NFULL + slot];
    const int chunk = (int)sc.oct[xcd * NFULL + slot] * ochunks + c;
    if (chunk >= chunks) return;

    const long long base = (long long)chunk * CHUNK;
    const int t = threadIdx.x;

    // cooperative nt load of this chunk's x (1536 f32x4 = 24KB)
    const f32x4* x4 = (const f32x4*)x;
    const long long nflt4 = ((long long)n_points * 3) / 4;
    for (int i = t; i < CHUNK * 3 / 4; i += 256) {
        long long gi = (long long)chunk * (CHUNK * 3 / 4) + i;
        f32x4 v = (gi < nflt4) ? __builtin_nontemporal_load(&x4[gi])
                               : (f32x4){0, 0, 0, 0};
        ((f32x4*)sx)[i] = v;
    }
    __syncthreads();

    const float rl = sc.res.r[lvl];                      // wave-uniform
    const f32x2* __restrict__ table = (const f32x2*)emb + (size_t)lvl * HS;
    f32x2* __restrict__ wsl = ws + (size_t)(lvl - NSMALL) * n_points;
    const unsigned P1 = 2654435761u, P2 = 805459861u;

    unsigned h[PPT];
    #pragma unroll
    for (int j = 0; j < PPT; j++) {
        const int p = t + j * 256;
        // exact f32 multiply+floor (matches jnp.floor(x*res) in f32);
        // int64 hash % 2^19 == uint32-wrapped sum & mask (2^19 | 2^32).
        unsigned c0 = (unsigned)(int)floorf(sx[p * 3 + 0] * rl);
        unsigned c1 = (unsigned)(int)floorf(sx[p * 3 + 1] * rl);
        unsigned c2 = (unsigned)(int)floorf(sx[p * 3 + 2] * rl);
        h[j] = (c0 + c1 * P1 + c2 * P2) & HASH_MASK;
    }
    f32x2 f[PPT];
    #pragma unroll
    for (int j = 0; j < PPT; j++) f[j] = table[h[j]];    // temporal: L2-resident
    #pragma unroll
    for (int j = 0; j < PPT; j++) {
        const long long n = base + t + j * 256;
        if (n < n_points) __builtin_nontemporal_store(f[j], &wsl[n]);
    }
}

// ------ Phase 2: transpose ws[11][N] -> out[N][32] + gather small levels ---
// Small tables (levels 0..4, 1.8MB total) are L2-resident on every XCD;
// their gathers mostly hit L2 and overlap the streaming.
__global__ __launch_bounds__(256) void he_transpose_kernel(
    const f32x2* __restrict__ ws,     // [11][N]
    const float* __restrict__ x,      // [N,3]
    const float* __restrict__ emb,    // [16][HS][2]
    float* __restrict__ out,          // [N,32]
    ResArr res, int n_points)
{
    __shared__ f32x2 sf[256 * 17];    // stride 17 f32x2: conflict-free
    __shared__ float sxx[256 * 3];
    const long long base = (long long)blockIdx.x * 256;
    const int t = threadIdx.x;
    const long long n = base + t;

    // coalesced x load for this tile (768 floats)
    for (int i = t; i < 768; i += 256) {
        long long gi = base * 3 + i;
        sxx[i] = (gi < (long long)n_points * 3) ? x[gi] : 0.0f;
    }
    __syncthreads();

    // small-level gathers (temporal: tables are small & reused)
    const float x0 = sxx[t * 3 + 0];
    const float x1 = sxx[t * 3 + 1];
    const float x2 = sxx[t * 3 + 2];
    const unsigned P1 = 2654435761u, P2 = 805459861u;
    const f32x2* __restrict__ e2 = (const f32x2*)emb;
    #pragma unroll
    for (int l = 0; l < NSMALL; l++) {
        const float rl = res.r[l];
        unsigned c0 = (unsigned)(int)floorf(x0 * rl);
        unsigned c1 = (unsigned)(int)floorf(x1 * rl);
        unsigned c2 = (unsigned)(int)floorf(x2 * rl);
        unsigned h = (c0 + c1 * P1 + c2 * P2) & HASH_MASK;
        sf[t * 17 + l] = e2[(size_t)l * HS + h];
    }
    // full levels from ws
    #pragma unroll
    for (int l = 0; l < NFULL; l++) {
        f32x2 v = (n < n_points)
            ? __builtin_nontemporal_load(&ws[(size_t)l * n_points + n])
            : (f32x2){0, 0};
        sf[t * 17 + NSMALL + l] = v;
    }
    __syncthreads();

    #pragma unroll
    for (int j = 0; j < 8; j++) {
        const int i = t + j * 256;     // f32x4 index within tile (0..2047)
        const int p = i >> 3;          // local point
        const int c2 = (i & 7) * 2;    // f32x2 offset in point row
        if (base + p < n_points) {
            f32x2 a = sf[p * 17 + c2];
            f32x2 b = sf[p * 17 + c2 + 1];
            f32x4 v = {a.x, a.y, b.x, b.y};
            __builtin_nontemporal_store(v, (f32x4*)out + (base * 8 + i));
        }
    }
}

// ---------------- Fallback (direct) if ws too small ------------------------
__global__ __launch_bounds__(256) void he_direct_kernel(
    const float* __restrict__ x, const float* __restrict__ emb,
    float* __restrict__ out, ResArr res, int n_points)
{
    __shared__ float sx[128 * 3];
    __shared__ float sres[NUM_LEVELS];
    const int t = threadIdx.x;
    const long long base = (long long)blockIdx.x * 128;
    if (t < NUM_LEVELS) sres[t] = res.r[t];
    for (int i = t; i < 384; i += 256) {
        long long gi = base * 3 + i;
        sx[i] = (gi < (long long)n_points * 3)
                    ? __builtin_nontemporal_load(&x[gi]) : 0.0f;
    }
    __syncthreads();
    const int lp = t & 7, pl = t >> 3, l0 = lp * 2;
    const float rA = sres[l0], rB = sres[l0 + 1];
    const unsigned P1 = 2654435761u, P2 = 805459861u;
    const f32x2* __restrict__ e2 = (const f32x2*)emb;
    unsigned ha[4], hb[4];
    #pragma unroll
    for (int j = 0; j < 4; j++) {
        const int pj = pl + j * 32;
        const float x0 = sx[pj * 3], x1 = sx[pj * 3 + 1], x2 = sx[pj * 3 + 2];
        unsigned a0 = (unsigned)(int)floorf(x0 * rA);
        unsigned a1 = (unsigned)(int)floorf(x1 * rA);
        unsigned a2 = (unsigned)(int)floorf(x2 * rA);
        unsigned b0 = (unsigned)(int)floorf(x0 * rB);
        unsigned b1 = (unsigned)(int)floorf(x1 * rB);
        unsigned b2 = (unsigned)(int)floorf(x2 * rB);
        ha[j] = (a0 + a1 * P1 + a2 * P2) & HASH_MASK;
        hb[j] = (b0 + b1 * P1 + b2 * P2) & HASH_MASK;
    }
    f32x2 fa[4], fb[4];
    #pragma unroll
    for (int j = 0; j < 4; j++) {
        fa[j] = e2[(size_t)l0 * HS + ha[j]];
        fb[j] = e2[((size_t)l0 + 1) * HS + hb[j]];
    }
    #pragma unroll
    for (int j = 0; j < 4; j++) {
        const long long n = base + pl + j * 32;
        if (n < n_points) {
            f32x4 v = {fa[j].x, fa[j].y, fb[j].x, fb[j].y};
            __builtin_nontemporal_store(v, (f32x4*)out + (n * 8 + lp));
        }
    }
}

extern "C" void kernel_launch(void* const* d_in, const int* in_sizes, int n_in,
                              void* d_out, int out_size, void* d_ws, size_t ws_size,
                              hipStream_t stream) {
    const float* x   = (const float*)d_in[0];
    const float* emb = (const float*)d_in[1];
    float* out = (float*)d_out;
    const int n = in_sizes[0] / 3;

    // Host-side RESOLUTIONS, identical arithmetic to the reference's Python
    // (libm pow + truncation) so level 15 (exact 2048.0) truncates identically.
    ResArr res;
    const double b = pow(128.0, 1.0 / 15.0);
    for (int i = 0; i < NUM_LEVELS; i++) {
        res.r[i] = (float)(long long)(16.0 * pow(b, (double)i));
    }

    const size_t ws_need = (size_t)NFULL * (size_t)n * sizeof(f32x2);
    if (ws_size >= ws_need) {
        Sched sc;
        sc.res = res;
        // full levels 5..15: 88 eighth-tasks -> exactly 11 per XCD,
        // same-level tasks adjacent in slot order.
        for (int q = 0; q < 88; q++) {
            int xcd = q / 11, slot = q % 11;
            sc.lvl[xcd * NFULL + slot] = (unsigned char)(5 + q / 8);
            sc.oct[xcd * NFULL + slot] = (unsigned char)(q % 8);
        }
        const int chunks = (n + CHUNK - 1) / CHUNK;
        const int ochunks = (chunks + 7) / 8;
        he_gather_kernel<<<8 * NFULL * ochunks, 256, 0, stream>>>(
            x, emb, (f32x2*)d_ws, sc, n, ochunks, chunks);
        he_transpose_kernel<<<(n + 255) / 256, 256, 0, stream>>>(
            (const f32x2*)d_ws, x, emb, out, res, n);
    } else {
        he_direct_kernel<<<(n + 127) / 128, 256, 0, stream>>>(x, emb, out, res, n);
    }
}

// Round 10
// 287.063 us; speedup vs baseline: 1.9129x; 1.0671x over previous
//
#include <hip/hip_runtime.h>
#include <math.h>

#define HASH_SIZE_LOG2 19
#define HASH_MASK ((1u << HASH_SIZE_LOG2) - 1u)
#define HS (1u << HASH_SIZE_LOG2)
#define NUM_LEVELS 16
#define NFULL 11                // levels 5..15: full-footprint tables in gather
#define NSMALL 5                // levels 0..4: gathered in transpose (L2-resident)
#define CHUNK 2048              // points per gather block
#define PPT 8                   // points per thread in gather

typedef float f32x2 __attribute__((ext_vector_type(2)));
typedef float f32x4 __attribute__((ext_vector_type(4)));

struct ResArr { float r[NUM_LEVELS]; };

// Static schedule for full levels 5..15: 11 levels x 8 eighths = 88 tasks ->
// 8 XCDs x 11 slots, exactly uniform. Same-level tasks adjacent in slot
// order so each XCD streams through <=3 distinct 4MB tables sequentially.
struct Sched {
    unsigned char lvl[88];    // [xcd][slot] slot=0..10
    unsigned char oct[88];    // eighth index 0..7
    ResArr res;
};

// ---------------- Phase 1: balanced level-pinned gather into ws[l-5][n] ----
// bid = (slot*ochunks + c)*8 + xcd ; XCD(bid) = bid%8 (round-robin dispatch).
// Round-9 lesson: the LDS x-stage (nt loads from HBM + barrier) was the
// serial head of every block. Now: NO LDS, NO barrier -- each thread issues
// 24 independent temporal x loads (L3-resident: x is 24MB, re-read 11x),
// then 8 gathers, then 8 nt stores. One deep MLP burst per thread.
// Table loads TEMPORAL (round-8: nt evicts from L2 too, killing residency).
__global__ __launch_bounds__(256) void he_gather_kernel(
    const float* __restrict__ x,      // [N,3]
    const float* __restrict__ emb,    // [16][HS][2]
    f32x2* __restrict__ ws,           // [11][N]
    Sched sc, int n_points, int ochunks, int chunks)
{
    const int bid = blockIdx.x;
    const int xcd = bid & 7;
    const int r = bid >> 3;
    const int slot = r / ochunks;
    const int c = r - slot * ochunks;
    const int lvl = sc.lvl[xcd * NFULL + slot];
    const int chunk = (int)sc.oct[xcd * NFULL + slot] * ochunks + c;
    if (chunk >= chunks) return;

    const long long base = (long long)chunk * CHUNK;
    const int t = threadIdx.x;
    const float rl = sc.res.r[lvl];                      // wave-uniform
    const f32x2* __restrict__ table = (const f32x2*)emb + (size_t)lvl * HS;
    f32x2* __restrict__ wsl = ws + (size_t)(lvl - NSMALL) * n_points;
    const unsigned P1 = 2654435761u, P2 = 805459861u;

    // 24 independent coord loads (12B/lane stride -> ~5 lanes/64B line).
    float xc0[PPT], xc1[PPT], xc2[PPT];
    #pragma unroll
    for (int j = 0; j < PPT; j++) {
        long long p = base + t + j * 256;
        if (p >= n_points) p = n_points - 1;   // safe dummy; store guarded
        xc0[j] = x[p * 3 + 0];
        xc1[j] = x[p * 3 + 1];
        xc2[j] = x[p * 3 + 2];
    }

    unsigned h[PPT];
    #pragma unroll
    for (int j = 0; j < PPT; j++) {
        // exact f32 multiply+floor (matches jnp.floor(x*res) in f32);
        // int64 hash % 2^19 == uint32-wrapped sum & mask (2^19 | 2^32).
        unsigned c0 = (unsigned)(int)floorf(xc0[j] * rl);
        unsigned c1 = (unsigned)(int)floorf(xc1[j] * rl);
        unsigned c2 = (unsigned)(int)floorf(xc2[j] * rl);
        h[j] = (c0 + c1 * P1 + c2 * P2) & HASH_MASK;
    }
    f32x2 f[PPT];
    #pragma unroll
    for (int j = 0; j < PPT; j++) f[j] = table[h[j]];    // temporal: L2-resident
    #pragma unroll
    for (int j = 0; j < PPT; j++) {
        const long long n = base + t + j * 256;
        if (n < n_points) __builtin_nontemporal_store(f[j], &wsl[n]);
    }
}

// ------ Phase 2: transpose ws[11][N] -> out[N][32] + gather small levels ---
// Small tables (levels 0..4, 1.8MB total) are L2-resident on every XCD;
// their gathers mostly hit L2 and overlap the streaming.
__global__ __launch_bounds__(256) void he_transpose_kernel(
    const f32x2* __restrict__ ws,     // [11][N]
    const float* __restrict__ x,      // [N,3]
    const float* __restrict__ emb,    // [16][HS][2]
    float* __restrict__ out,          // [N,32]
    ResArr res, int n_points)
{
    __shared__ f32x2 sf[256 * 17];    // stride 17 f32x2: conflict-free
    __shared__ float sxx[256 * 3];
    const long long base = (long long)blockIdx.x * 256;
    const int t = threadIdx.x;
    const long long n = base + t;

    // coalesced x load for this tile (768 floats)
    for (int i = t; i < 768; i += 256) {
        long long gi = base * 3 + i;
        sxx[i] = (gi < (long long)n_points * 3) ? x[gi] : 0.0f;
    }
    __syncthreads();

    // small-level gathers (temporal: tables are small & reused)
    const float x0 = sxx[t * 3 + 0];
    const float x1 = sxx[t * 3 + 1];
    const float x2 = sxx[t * 3 + 2];
    const unsigned P1 = 2654435761u, P2 = 805459861u;
    const f32x2* __restrict__ e2 = (const f32x2*)emb;
    #pragma unroll
    for (int l = 0; l < NSMALL; l++) {
        const float rl = res.r[l];
        unsigned c0 = (unsigned)(int)floorf(x0 * rl);
        unsigned c1 = (unsigned)(int)floorf(x1 * rl);
        unsigned c2 = (unsigned)(int)floorf(x2 * rl);
        unsigned h = (c0 + c1 * P1 + c2 * P2) & HASH_MASK;
        sf[t * 17 + l] = e2[(size_t)l * HS + h];
    }
    // full levels from ws
    #pragma unroll
    for (int l = 0; l < NFULL; l++) {
        f32x2 v = (n < n_points)
            ? __builtin_nontemporal_load(&ws[(size_t)l * n_points + n])
            : (f32x2){0, 0};
        sf[t * 17 + NSMALL + l] = v;
    }
    __syncthreads();

    #pragma unroll
    for (int j = 0; j < 8; j++) {
        const int i = t + j * 256;     // f32x4 index within tile (0..2047)
        const int p = i >> 3;          // local point
        const int c2 = (i & 7) * 2;    // f32x2 offset in point row
        if (base + p < n_points) {
            f32x2 a = sf[p * 17 + c2];
            f32x2 b = sf[p * 17 + c2 + 1];
            f32x4 v = {a.x, a.y, b.x, b.y};
            __builtin_nontemporal_store(v, (f32x4*)out + (base * 8 + i));
        }
    }
}

// ---------------- Fallback (direct) if ws too small ------------------------
__global__ __launch_bounds__(256) void he_direct_kernel(
    const float* __restrict__ x, const float* __restrict__ emb,
    float* __restrict__ out, ResArr res, int n_points)
{
    __shared__ float sx[128 * 3];
    __shared__ float sres[NUM_LEVELS];
    const int t = threadIdx.x;
    const long long base = (long long)blockIdx.x * 128;
    if (t < NUM_LEVELS) sres[t] = res.r[t];
    for (int i = t; i < 384; i += 256) {
        long long gi = base * 3 + i;
        sx[i] = (gi < (long long)n_points * 3) ? x[gi] : 0.0f;
    }
    __syncthreads();
    const int lp = t & 7, pl = t >> 3, l0 = lp * 2;
    const float rA = sres[l0], rB = sres[l0 + 1];
    const unsigned P1 = 2654435761u, P2 = 805459861u;
    const f32x2* __restrict__ e2 = (const f32x2*)emb;
    unsigned ha[4], hb[4];
    #pragma unroll
    for (int j = 0; j < 4; j++) {
        const int pj = pl + j * 32;
        const float x0 = sx[pj * 3], x1 = sx[pj * 3 + 1], x2 = sx[pj * 3 + 2];
        unsigned a0 = (unsigned)(int)floorf(x0 * rA);
        unsigned a1 = (unsigned)(int)floorf(x1 * rA);
        unsigned a2 = (unsigned)(int)floorf(x2 * rA);
        unsigned b0 = (unsigned)(int)floorf(x0 * rB);
        unsigned b1 = (unsigned)(int)floorf(x1 * rB);
        unsigned b2 = (unsigned)(int)floorf(x2 * rB);
        ha[j] = (a0 + a1 * P1 + a2 * P2) & HASH_MASK;
        hb[j] = (b0 + b1 * P1 + b2 * P2) & HASH_MASK;
    }
    f32x2 fa[4], fb[4];
    #pragma unroll
    for (int j = 0; j < 4; j++) {
        fa[j] = e2[(size_t)l0 * HS + ha[j]];
        fb[j] = e2[((size_t)l0 + 1) * HS + hb[j]];
    }
    #pragma unroll
    for (int j = 0; j < 4; j++) {
        const long long n = base + pl + j * 32;
        if (n < n_points) {
            f32x4 v = {fa[j].x, fa[j].y, fb[j].x, fb[j].y};
            __builtin_nontemporal_store(v, (f32x4*)out + (n * 8 + lp));
        }
    }
}

extern "C" void kernel_launch(void* const* d_in, const int* in_sizes, int n_in,
                              void* d_out, int out_size, void* d_ws, size_t ws_size,
                              hipStream_t stream) {
    const float* x   = (const float*)d_in[0];
    const float* emb = (const float*)d_in[1];
    float* out = (float*)d_out;
    const int n = in_sizes[0] / 3;

    // Host-side RESOLUTIONS, identical arithmetic to the reference's Python
    // (libm pow + truncation) so level 15 (exact 2048.0) truncates identically.
    ResArr res;
    const double b = pow(128.0, 1.0 / 15.0);
    for (int i = 0; i < NUM_LEVELS; i++) {
        res.r[i] = (float)(long long)(16.0 * pow(b, (double)i));
    }

    const size_t ws_need = (size_t)NFULL * (size_t)n * sizeof(f32x2);
    if (ws_size >= ws_need) {
        Sched sc;
        sc.res = res;
        // full levels 5..15: 88 eighth-tasks -> exactly 11 per XCD,
        // same-level tasks adjacent in slot order.
        for (int q = 0; q < 88; q++) {
            int xcd = q / 11, slot = q % 11;
            sc.lvl[xcd * NFULL + slot] = (unsigned char)(5 + q / 8);
            sc.oct[xcd * NFULL + slot] = (unsigned char)(q % 8);
        }
        const int chunks = (n + CHUNK - 1) / CHUNK;
        const int ochunks = (chunks + 7) / 8;
        he_gather_kernel<<<8 * NFULL * ochunks, 256, 0, stream>>>(
            x, emb, (f32x2*)d_ws, sc, n, ochunks, chunks);
        he_transpose_kernel<<<(n + 255) / 256, 256, 0, stream>>>(
            (const f32x2*)d_ws, x, emb, out, res, n);
    } else {
        he_direct_kernel<<<(n + 127) / 128, 256, 0, stream>>>(x, emb, out, res, n);
    }
}